// Round 3
// baseline (243.184 us; speedup 1.0000x reference)
//
#include <hip/hip_runtime.h>
#include <stdint.h>

typedef unsigned int u32;
typedef unsigned long long u64;

#define BATCH 16
#define NANCH 25200
#define NCLS 80
#define ROWF 85
#define MAXC 1000
#define CONF_T 0.25f
#define IOU_T 0.45f
#define EPS_F 1e-7f
#define TILE 64
#define NTILES ((NANCH + TILE - 1) / TILE)   /* 394, last tile = 48 */

// IoU exactly as the numpy/JAX reference computes it (no FMA contraction:
// keep inter's rounding separate from the union subtraction).
__device__ __forceinline__ float iou_ref(float4 a, float4 b) {
#pragma clang fp contract(off)
  float ai = (a.z - a.x) * (a.w - a.y);
  float aj = (b.z - b.x) * (b.w - b.y);
  float ltx = fmaxf(a.x, b.x), lty = fmaxf(a.y, b.y);
  float rbx = fminf(a.z, b.z), rby = fminf(a.w, b.w);
  float wx = fmaxf(rbx - ltx, 0.0f), wy = fmaxf(rby - lty, 0.0f);
  float inter = wx * wy;
  return inter / (ai + aj - inter + EPS_F);
}

// K1: LDS-staged coalesced scoring. Emits 32-bit keys:
//   valid:   (conf_bits - 0x3E800000) << 7 | cls   (conf in (0.25,1) => 24-bit
//            rebased value; monotone in conf; >= 0x80)
//   invalid: 0
__global__ __launch_bounds__(256) void k1_score(const float* __restrict__ pred,
                                                u32* __restrict__ keys32) {
  __shared__ float srow[TILE * ROWF];     // 21760 B
  __shared__ u32 skeys[TILE];
  int tid = threadIdx.x;
  int b = blockIdx.y;
  int t0 = blockIdx.x * TILE;
  int ntile = (t0 + TILE <= NANCH) ? TILE : (NANCH - t0);   // 64 or 48
  int nf4 = (ntile * ROWF) >> 2;          // 1360 or 1020 (both exact)

  const float4* src4 = (const float4*)(pred + ((size_t)b * NANCH + t0) * ROWF);
  float4* smem4 = (float4*)srow;
#pragma unroll
  for (int k = 0; k < 6; ++k) {
    int i = k * 256 + tid;
    if (i < nf4) smem4[i] = src4[i];
  }
  __syncthreads();

  int a = tid >> 2;          // anchor in tile
  int q = tid & 3;           // class-quarter
  float best = -1e30f;
  int bidx = 0;
  float obj = 0.0f;
  if (a < ntile) {
    const float* row = srow + a * ROWF;
    obj = row[4];
    int c0 = q * 20;
#pragma unroll
    for (int c = 0; c < 20; ++c) {
      float s = row[5 + c0 + c] * obj;        // exact same mul as reference
      if (s > best) { best = s; bidx = c0 + c; }
    }
  }
  // exact tie rule: larger score wins; equal score -> lower class index wins
#pragma unroll
  for (int off = 1; off < 4; off <<= 1) {
    float ob = __shfl_xor(best, off);
    int oi = __shfl_xor(bidx, off);
    if (ob > best || (ob == best && oi < bidx)) { best = ob; bidx = oi; }
  }
  if (q == 0 && a < ntile) {
    bool valid = (obj > CONF_T) && (best > CONF_T);
    u32 k = valid ? (((__float_as_uint(best) - 0x3E800000u) << 7) | (u32)bidx)
                  : 0u;
    skeys[a] = k;
  }
  __syncthreads();
  if (tid < ntile) keys32[(size_t)b * NANCH + t0 + tid] = skeys[tid];
}

// K2: top-1000 via ONE 13-bit histogram pass (bin-floor cut = conservative
// superset of the exact top-1000). De-spilled: keys are STREAMED through the
// histogram (not cached in 25 regs) and re-read from global (L2-hot, K1 just
// wrote them) for the compact pass — keeps live VGPRs ~40 under the 128-VGPR
// cap of a 1024-thread block so no scratch traffic is possible.
// Then bitonic sort of exact 64-bit order keys; n==1024 path sorts in
// REGISTERS: shfl_xor for intra-wave strides (45 phases, no barrier), LDS
// round-trip only for the 10 cross-wave phases.
__global__ __launch_bounds__(1024) void k2_select(const float* __restrict__ pred,
                                                  const u32* __restrict__ keys32,
                                                  float* __restrict__ selbox,
                                                  float* __restrict__ offbox,
                                                  float2* __restrict__ selmeta) {
  int b = blockIdx.x;
  int tid = threadIdx.x;
  int wv = tid >> 6, lane = tid & 63;
  __shared__ u32 h[8192];          // 32 KB
  __shared__ u64 skey[2048];       // 16 KB
  __shared__ u32 wsum[16];
  __shared__ u32 sh_fbin;
  __shared__ u32 scount;

  const u32* kb = keys32 + (size_t)b * NANCH;
  for (int i = tid; i < 8192; i += 1024) h[i] = 0;
  if (tid == 0) { sh_fbin = 0; scount = 0; }
  skey[tid] = ~0ull;
  skey[tid + 1024] = ~0ull;
  __syncthreads();
  // pass 1: streaming histogram (no register cache)
#pragma unroll
  for (int j = 0; j < 25; ++j) {
    int i = tid + j * 1024;
    u32 k = (i < NANCH) ? kb[i] : 0u;      // only j==24 can be OOB
    if (k >= 0x80u) atomicAdd(&h[k >> 18], 1u);   // valid keys only
  }
  __syncthreads();
  // suffix-sum select over 8192 bins (8 per thread): smallest bin f with
  // count(keys in bins >= f) >= 1000
  u32 a[8]; u32 lsum = 0;
#pragma unroll
  for (int k = 0; k < 8; ++k) { a[k] = h[8 * tid + k]; lsum += a[k]; }
  u32 suf = lsum;
#pragma unroll
  for (int off = 1; off < 64; off <<= 1) {
    u32 tv = __shfl_down(suf, off);
    if (lane + off < 64) suf += tv;
  }
  if (lane == 0) wsum[wv] = suf;
  __syncthreads();
  u32 base = 0;
#pragma unroll
  for (int w2 = 0; w2 < 16; ++w2) if (w2 > wv) base += wsum[w2];
  u32 e = base + suf - lsum;       // count of keys in bins strictly above 8t+7
#pragma unroll
  for (int k = 7; k >= 0; --k) {
    u32 inc = e + a[k];
    if ((int)inc >= MAXC && (int)e < MAXC) sh_fbin = (u32)(8 * tid + k);
    e = inc;
  }
  __syncthreads();
  u32 cut = sh_fbin << 18;
  // pass 2: re-read keys (L2-hot) and compact; reconstruct exact order key.
  // Wave-aggregated allocation: one LDS atomic per wave per round; placement
  // order is irrelevant — full sort follows.
#pragma unroll
  for (int j = 0; j < 25; ++j) {
    int i = tid + j * 1024;
    u32 k = (i < NANCH) ? kb[i] : 0u;
    bool take = (k >= cut) && (k != 0u);
    u64 mask = __ballot(take ? 1 : 0);
    u32 wbase = 0;
    if (lane == 0 && mask != 0ull)
      wbase = atomicAdd(&scount, (u32)__popcll(mask));
    wbase = (u32)__shfl((int)wbase, 0);
    if (take) {
      u64 sk = ((u64)(k >> 7) << 32) |
               (u64)(((32767u - (u32)i) << 7) | (k & 127u));
      u32 p = wbase + (u32)__popcll(mask & ((1ull << lane) - 1ull));
      if (p < 2048) skey[p] = ~sk;   // ascending on ~key == descending key
    }
  }
  __syncthreads();
  u64 v;                                     // this thread's sorted element
  if (scount <= 1024u) {
    // ---- register bitonic over 1024 (one element/thread) ----
    v = skey[tid];
    for (u32 kk = 2; kk <= 1024; kk <<= 1) {
      for (u32 j = kk >> 1; j > 0; j >>= 1) {
        bool up = ((tid & kk) == 0);         // ascending segment
        bool low = ((tid & j) == 0);         // this thread is the low index
        if (j >= 64) {
          skey[tid] = v;
          __syncthreads();
          u64 o = skey[tid ^ j];
          bool takemin = (up == low);
          v = takemin ? (v < o ? v : o) : (v > o ? v : o);
          __syncthreads();                   // protect skey before next store
        } else {
          u64 o = __shfl_xor(v, (int)j);
          bool takemin = (up == low);
          v = takemin ? (v < o ? v : o) : (v > o ? v : o);
        }
      }
    }
  } else {
    // ---- fallback: in-LDS bitonic over 2048 ----
    for (u32 kk = 2; kk <= 2048; kk <<= 1) {
      for (u32 j = kk >> 1; j > 0; j >>= 1) {
        for (int idx = tid; idx < 2048; idx += 1024) {
          u32 ixj = (u32)idx ^ j;
          if (ixj > (u32)idx) {
            u64 x = skey[idx], y = skey[ixj];
            bool up = ((idx & kk) == 0);
            if (up ? (x > y) : (x < y)) { skey[idx] = y; skey[ixj] = x; }
          }
        }
        __syncthreads();
      }
    }
    v = skey[tid];
  }
  // epilogue: gather + xywh2xyxy + class-offset boxes
  if (tid < MAXC) {
    u64 k = ~v;
    u32 confpart = (u32)(k >> 32);
    u32 lo = (u32)k;
    bool valid = confpart != 0u;     // pad and invalid both give 0
    float conf = 0.0f, x1 = 0.0f, y1 = 0.0f, x2 = 0.0f, y2 = 0.0f;
    float cf = 0.0f, offv = 0.0f;
    if (valid) {
      u32 nidx = 32767u - ((lo >> 7) & 0x7FFFu);
      u32 ci = lo & 127u;
      conf = __uint_as_float(confpart + 0x3E800000u);   // exact bits restored
      const float* pr = pred + ((size_t)b * NANCH + nidx) * ROWF;
      float x = pr[0], y = pr[1], w = pr[2], h2 = pr[3];
      x1 = x - w * 0.5f; y1 = y - h2 * 0.5f;
      x2 = x + w * 0.5f; y2 = y + h2 * 0.5f;
      cf = (float)ci; offv = cf * 4096.0f;
    }
    int o = b * MAXC + tid;
    ((float4*)selbox)[o] = make_float4(x1, y1, x2, y2);
    ((float4*)offbox)[o] = make_float4(x1 + offv, y1 + offv, x2 + offv, y2 + offv);
    selmeta[o] = make_float2(conf, cf);
  }
}

// K3: transposed suppression bits, stored WORD-MAJOR dt[b][w][i] so K4's
// 16-block load is coalesced. Triangular: only words w <= i>>6 can hold
// j < i bits; higher words are written as zeros (myword init).
__global__ __launch_bounds__(256) void k3_dt(const float4* __restrict__ offbox4,
                                             u64* __restrict__ dt) {
  int wid = blockIdx.x * 4 + (threadIdx.x >> 6);   // b*MAXC + i
  int lane = threadIdx.x & 63;
  int b = wid / MAXC;
  int i = wid % MAXC;
  float4 bi = offbox4[b * MAXC + i];
  u64 myword = 0;
  int wmax = i >> 6;                               // uniform per wave
  for (int w = 0; w <= wmax; ++w) {
    int j = w * 64 + lane;
    int jc = (j < MAXC) ? j : 0;
    float4 bj = offbox4[b * MAXC + jc];
    float iou = iou_ref(bi, bj);
    bool bit = (iou > IOU_T) && (j < i);            // j<i implies j<MAXC
    u64 bal = __ballot(bit ? 1 : 0);
    if (lane == w) myword = bal;
  }
  if (lane < 16) dt[((size_t)b * 16 + lane) * MAXC + i] = myword;
}

// K4: Jacobi fixed-point of keep[i] = valid[i] & ~OR_{j<i}(keep[j]&D[j,i]).
// Unique fixed point == greedy NMS; converges in max-chain-depth passes.
// 2 barriers/pass via double-buffered changed flags.
__global__ __launch_bounds__(1024) void k4_jacobi(const u64* __restrict__ dt,
                                                  const float2* __restrict__ selmeta,
                                                  const float* __restrict__ selbox,
                                                  float* __restrict__ out) {
  int b = blockIdx.x;
  int tid = threadIdx.x;
  int wv = tid >> 6, lane = tid & 63;
  __shared__ u64 keepv[16];
  __shared__ u32 changed2[2];
  bool valid = false;
  float2 meta = make_float2(0.0f, 0.0f);
  u64 dtr[16];
  if (tid < MAXC) {
    meta = selmeta[b * MAXC + tid];
    valid = meta.x > 0.0f;                 // conf>0 <=> valid
#pragma unroll
    for (int w = 0; w < 16; ++w) dtr[w] = dt[((size_t)b * 16 + w) * MAXC + tid];
  } else {
#pragma unroll
    for (int w = 0; w < 16; ++w) dtr[w] = 0ull;
  }
  u64 bal0 = __ballot(valid ? 1 : 0);
  if (tid == 0) { changed2[0] = 0; changed2[1] = 0; }
  if (lane == 0) keepv[wv] = bal0;
  __syncthreads();
  for (int pass = 0; pass < MAXC; ++pass) {
    u64 kv[16];
#pragma unroll
    for (int w = 0; w < 16; ++w) kv[w] = keepv[w];
    u64 s = 0;
#pragma unroll
    for (int w = 0; w < 16; ++w) s |= dtr[w] & kv[w];
    bool nk = valid && (s == 0ull);
    u64 bal = __ballot(nk ? 1 : 0);
    __syncthreads();                       // A: all keepv/flag reads done
    if (lane == 0 && bal != kv[wv]) {
      keepv[wv] = bal;
      atomicOr(&changed2[pass & 1], 1u);
    }
    __syncthreads();                       // B: writes visible
    u32 ch = changed2[pass & 1];
    if (tid == 0) changed2[(pass & 1) ^ 1] = 0;  // reset OTHER slot (consumed
                                                 // last pass; reuse in 2)
    if (!ch) break;                        // ch uniform -> uniform exit
  }
  if (tid < MAXC) {
    bool kept = ((keepv[wv] >> lane) & 1ull) != 0ull;
    size_t o = (size_t)b * MAXC + tid;
    float4 bx = ((const float4*)selbox)[o];
    float* orow = out + o * 6;
    orow[0] = kept ? bx.x : 0.0f;
    orow[1] = kept ? bx.y : 0.0f;
    orow[2] = kept ? bx.z : 0.0f;
    orow[3] = kept ? bx.w : 0.0f;
    orow[4] = kept ? meta.x : 0.0f;
    orow[5] = kept ? meta.y : 0.0f;
    out[(size_t)BATCH * MAXC * 6 + o] = kept ? 1.0f : 0.0f;
  }
}

extern "C" void kernel_launch(void* const* d_in, const int* in_sizes, int n_in,
                              void* d_out, int out_size, void* d_ws, size_t ws_size,
                              hipStream_t stream) {
  const float* pred = (const float*)d_in[0];
  float* out = (float*)d_out;
  char* ws = (char*)d_ws;
  size_t off = 0;
  auto alloc = [&](size_t bytes) -> void* {
    void* p = ws + off;
    off = (off + bytes + 255) & ~(size_t)255;
    return p;
  };
  u32* keys32   = (u32*)alloc((size_t)BATCH * NANCH * 4);
  float* selbox = (float*)alloc((size_t)BATCH * MAXC * 4 * 4);
  float* offbox = (float*)alloc((size_t)BATCH * MAXC * 4 * 4);
  float2* selmeta = (float2*)alloc((size_t)BATCH * MAXC * 8);
  u64* dt       = (u64*)alloc((size_t)BATCH * 16 * MAXC * 8);
  (void)ws_size; (void)in_sizes; (void)n_in; (void)out_size;

  dim3 g1(NTILES, BATCH);
  k1_score<<<g1, 256, 0, stream>>>(pred, keys32);
  k2_select<<<BATCH, 1024, 0, stream>>>(pred, keys32, selbox, offbox, selmeta);
  k3_dt<<<(BATCH * MAXC) / 4, 256, 0, stream>>>((const float4*)offbox, dt);
  k4_jacobi<<<BATCH, 1024, 0, stream>>>(dt, selmeta, selbox, out);
}

// Round 4
// 237.767 us; speedup vs baseline: 1.0228x; 1.0228x over previous
//
#include <hip/hip_runtime.h>
#include <stdint.h>

typedef unsigned int u32;
typedef unsigned long long u64;

#define BATCH 16
#define NANCH 25200
#define NCLS 80
#define ROWF 85
#define MAXC 1000
#define CONF_T 0.25f
#define IOU_T 0.45f
#define EPS_F 1e-7f
#define TILE 64
#define NTILES ((NANCH + TILE - 1) / TILE)   /* 394, last tile = 48 */

// IoU exactly as the numpy/JAX reference computes it (no FMA contraction:
// keep inter's rounding separate from the union subtraction).
__device__ __forceinline__ float iou_ref(float4 a, float4 b) {
#pragma clang fp contract(off)
  float ai = (a.z - a.x) * (a.w - a.y);
  float aj = (b.z - b.x) * (b.w - b.y);
  float ltx = fmaxf(a.x, b.x), lty = fmaxf(a.y, b.y);
  float rbx = fminf(a.z, b.z), rby = fminf(a.w, b.w);
  float wx = fmaxf(rbx - ltx, 0.0f), wy = fmaxf(rby - lty, 0.0f);
  float inter = wx * wy;
  return inter / (ai + aj - inter + EPS_F);
}

// K1: LDS-staged coalesced scoring. Emits 32-bit keys:
//   valid:   (conf_bits - 0x3E800000) << 7 | cls   (conf in (0.25,1) => 24-bit
//            rebased value; monotone in conf; >= 0x80)
//   invalid: 0
__global__ __launch_bounds__(256) void k1_score(const float* __restrict__ pred,
                                                u32* __restrict__ keys32) {
  __shared__ float srow[TILE * ROWF];     // 21760 B
  __shared__ u32 skeys[TILE];
  int tid = threadIdx.x;
  int b = blockIdx.y;
  int t0 = blockIdx.x * TILE;
  int ntile = (t0 + TILE <= NANCH) ? TILE : (NANCH - t0);   // 64 or 48
  int nf4 = (ntile * ROWF) >> 2;          // 1360 or 1020 (both exact)

  const float4* src4 = (const float4*)(pred + ((size_t)b * NANCH + t0) * ROWF);
  float4* smem4 = (float4*)srow;
#pragma unroll
  for (int k = 0; k < 6; ++k) {
    int i = k * 256 + tid;
    if (i < nf4) smem4[i] = src4[i];
  }
  __syncthreads();

  int a = tid >> 2;          // anchor in tile
  int q = tid & 3;           // class-quarter
  float best = -1e30f;
  int bidx = 0;
  float obj = 0.0f;
  if (a < ntile) {
    const float* row = srow + a * ROWF;
    obj = row[4];
    int c0 = q * 20;
#pragma unroll
    for (int c = 0; c < 20; ++c) {
      float s = row[5 + c0 + c] * obj;        // exact same mul as reference
      if (s > best) { best = s; bidx = c0 + c; }
    }
  }
  // exact tie rule: larger score wins; equal score -> lower class index wins
#pragma unroll
  for (int off = 1; off < 4; off <<= 1) {
    float ob = __shfl_xor(best, off);
    int oi = __shfl_xor(bidx, off);
    if (ob > best || (ob == best && oi < bidx)) { best = ob; bidx = oi; }
  }
  if (q == 0 && a < ntile) {
    bool valid = (obj > CONF_T) && (best > CONF_T);
    u32 k = valid ? (((__float_as_uint(best) - 0x3E800000u) << 7) | (u32)bidx)
                  : 0u;
    skeys[a] = k;
  }
  __syncthreads();
  if (tid < ntile) keys32[(size_t)b * NANCH + t0 + tid] = skeys[tid];
}

// K2: top-1000 via ONE 13-bit histogram pass (bin-floor cut = conservative
// superset of the exact top-1000), keys cached in 25 registers/thread,
// compact (wave-aggregated LDS atomic), bitonic sort of exact 64-bit order
// keys. n==1024 path sorts in REGISTERS: shfl_xor for intra-wave strides
// (45 phases, no barrier), LDS round-trip only for the 10 cross-wave phases.
__global__ __launch_bounds__(1024) void k2_select(const float* __restrict__ pred,
                                                  const u32* __restrict__ keys32,
                                                  float* __restrict__ selbox,
                                                  float* __restrict__ offbox,
                                                  float2* __restrict__ selmeta) {
  int b = blockIdx.x;
  int tid = threadIdx.x;
  int wv = tid >> 6, lane = tid & 63;
  __shared__ u32 h[8192];          // 32 KB
  __shared__ u64 skey[2048];       // 16 KB
  __shared__ u32 wsum[16];
  __shared__ u32 sh_fbin;
  __shared__ u32 scount;

  const u32* kb = keys32 + (size_t)b * NANCH;
  u32 kreg[25];
#pragma unroll
  for (int j = 0; j < 25; ++j) {
    int i = tid + j * 1024;
    kreg[j] = (i < NANCH) ? kb[i] : 0u;    // only j==24 can be OOB
  }
  for (int i = tid; i < 8192; i += 1024) h[i] = 0;
  if (tid == 0) { sh_fbin = 0; scount = 0; }
  skey[tid] = ~0ull;
  skey[tid + 1024] = ~0ull;
  __syncthreads();
#pragma unroll
  for (int j = 0; j < 25; ++j) {
    u32 k = kreg[j];
    if (k >= 0x80u) atomicAdd(&h[k >> 18], 1u);   // valid keys only
  }
  __syncthreads();
  // suffix-sum select over 8192 bins (8 per thread): smallest bin f with
  // count(keys in bins >= f) >= 1000
  u32 a[8]; u32 lsum = 0;
#pragma unroll
  for (int k = 0; k < 8; ++k) { a[k] = h[8 * tid + k]; lsum += a[k]; }
  u32 suf = lsum;
#pragma unroll
  for (int off = 1; off < 64; off <<= 1) {
    u32 tv = __shfl_down(suf, off);
    if (lane + off < 64) suf += tv;
  }
  if (lane == 0) wsum[wv] = suf;
  __syncthreads();
  u32 base = 0;
#pragma unroll
  for (int w2 = 0; w2 < 16; ++w2) if (w2 > wv) base += wsum[w2];
  u32 e = base + suf - lsum;       // count of keys in bins strictly above 8t+7
#pragma unroll
  for (int k = 7; k >= 0; --k) {
    u32 inc = e + a[k];
    if ((int)inc >= MAXC && (int)e < MAXC) sh_fbin = (u32)(8 * tid + k);
    e = inc;
  }
  __syncthreads();
  u32 cut = sh_fbin << 18;
  // compact from registers; reconstruct exact order key.
  // Wave-aggregated allocation: one LDS atomic per wave per round instead of
  // one per surviving key (placement order is irrelevant — full sort follows).
#pragma unroll
  for (int j = 0; j < 25; ++j) {
    u32 k = kreg[j];
    bool take = (k >= cut) && (k != 0u);
    u64 mask = __ballot(take ? 1 : 0);
    u32 wbase = 0;
    if (lane == 0 && mask != 0ull)
      wbase = atomicAdd(&scount, (u32)__popcll(mask));
    wbase = (u32)__shfl((int)wbase, 0);
    if (take) {
      int i = tid + j * 1024;
      u64 sk = ((u64)(k >> 7) << 32) |
               (u64)(((32767u - (u32)i) << 7) | (k & 127u));
      u32 p = wbase + (u32)__popcll(mask & ((1ull << lane) - 1ull));
      if (p < 2048) skey[p] = ~sk;   // ascending on ~key == descending key
    }
  }
  __syncthreads();
  u64 v;                                     // this thread's sorted element
  if (scount <= 1024u) {
    // ---- register bitonic over 1024 (one element/thread) ----
    v = skey[tid];
    for (u32 kk = 2; kk <= 1024; kk <<= 1) {
      for (u32 j = kk >> 1; j > 0; j >>= 1) {
        bool up = ((tid & kk) == 0);         // ascending segment
        bool low = ((tid & j) == 0);         // this thread is the low index
        if (j >= 64) {
          skey[tid] = v;
          __syncthreads();
          u64 o = skey[tid ^ j];
          bool takemin = (up == low);
          v = takemin ? (v < o ? v : o) : (v > o ? v : o);
          __syncthreads();                   // protect skey before next store
        } else {
          u64 o = __shfl_xor(v, (int)j);
          bool takemin = (up == low);
          v = takemin ? (v < o ? v : o) : (v > o ? v : o);
        }
      }
    }
  } else {
    // ---- fallback: in-LDS bitonic over 2048 ----
    for (u32 kk = 2; kk <= 2048; kk <<= 1) {
      for (u32 j = kk >> 1; j > 0; j >>= 1) {
        for (int idx = tid; idx < 2048; idx += 1024) {
          u32 ixj = (u32)idx ^ j;
          if (ixj > (u32)idx) {
            u64 x = skey[idx], y = skey[ixj];
            bool up = ((idx & kk) == 0);
            if (up ? (x > y) : (x < y)) { skey[idx] = y; skey[ixj] = x; }
          }
        }
        __syncthreads();
      }
    }
    v = skey[tid];
  }
  // epilogue: gather + xywh2xyxy + class-offset boxes
  if (tid < MAXC) {
    u64 k = ~v;
    u32 confpart = (u32)(k >> 32);
    u32 lo = (u32)k;
    bool valid = confpart != 0u;     // pad and invalid both give 0
    float conf = 0.0f, x1 = 0.0f, y1 = 0.0f, x2 = 0.0f, y2 = 0.0f;
    float cf = 0.0f, offv = 0.0f;
    if (valid) {
      u32 nidx = 32767u - ((lo >> 7) & 0x7FFFu);
      u32 ci = lo & 127u;
      conf = __uint_as_float(confpart + 0x3E800000u);   // exact bits restored
      const float* pr = pred + ((size_t)b * NANCH + nidx) * ROWF;
      float x = pr[0], y = pr[1], w = pr[2], h2 = pr[3];
      x1 = x - w * 0.5f; y1 = y - h2 * 0.5f;
      x2 = x + w * 0.5f; y2 = y + h2 * 0.5f;
      cf = (float)ci; offv = cf * 4096.0f;
    }
    int o = b * MAXC + tid;
    ((float4*)selbox)[o] = make_float4(x1, y1, x2, y2);
    ((float4*)offbox)[o] = make_float4(x1 + offv, y1 + offv, x2 + offv, y2 + offv);
    selmeta[o] = make_float2(conf, cf);
  }
}

// K3: transposed suppression bits, stored WORD-MAJOR dt[b][w][i] so K4's
// 16-block load is coalesced. Triangular: only words w <= i>>6 can hold
// j < i bits; higher words are written as zeros (myword init).
__global__ __launch_bounds__(256) void k3_dt(const float4* __restrict__ offbox4,
                                             u64* __restrict__ dt) {
  int wid = blockIdx.x * 4 + (threadIdx.x >> 6);   // b*MAXC + i
  int lane = threadIdx.x & 63;
  int b = wid / MAXC;
  int i = wid % MAXC;
  float4 bi = offbox4[b * MAXC + i];
  u64 myword = 0;
  int wmax = i >> 6;                               // uniform per wave
  for (int w = 0; w <= wmax; ++w) {
    int j = w * 64 + lane;
    int jc = (j < MAXC) ? j : 0;
    float4 bj = offbox4[b * MAXC + jc];
    float iou = iou_ref(bi, bj);
    bool bit = (iou > IOU_T) && (j < i);            // j<i implies j<MAXC
    u64 bal = __ballot(bit ? 1 : 0);
    if (lane == w) myword = bal;
  }
  if (lane < 16) dt[((size_t)b * 16 + lane) * MAXC + i] = myword;
}

// K4: Jacobi fixed-point of keep[i] = valid[i] & ~OR_{j<i}(keep[j]&D[j,i]).
// Unique fixed point == greedy NMS; converges in max-chain-depth passes.
// 2 barriers/pass via double-buffered changed flags.
__global__ __launch_bounds__(1024) void k4_jacobi(const u64* __restrict__ dt,
                                                  const float2* __restrict__ selmeta,
                                                  const float* __restrict__ selbox,
                                                  float* __restrict__ out) {
  int b = blockIdx.x;
  int tid = threadIdx.x;
  int wv = tid >> 6, lane = tid & 63;
  __shared__ u64 keepv[16];
  __shared__ u32 changed2[2];
  bool valid = false;
  float2 meta = make_float2(0.0f, 0.0f);
  u64 dtr[16];
  if (tid < MAXC) {
    meta = selmeta[b * MAXC + tid];
    valid = meta.x > 0.0f;                 // conf>0 <=> valid
#pragma unroll
    for (int w = 0; w < 16; ++w) dtr[w] = dt[((size_t)b * 16 + w) * MAXC + tid];
  } else {
#pragma unroll
    for (int w = 0; w < 16; ++w) dtr[w] = 0ull;
  }
  u64 bal0 = __ballot(valid ? 1 : 0);
  if (tid == 0) { changed2[0] = 0; changed2[1] = 0; }
  if (lane == 0) keepv[wv] = bal0;
  __syncthreads();
  for (int pass = 0; pass < MAXC; ++pass) {
    u64 kv[16];
#pragma unroll
    for (int w = 0; w < 16; ++w) kv[w] = keepv[w];
    u64 s = 0;
#pragma unroll
    for (int w = 0; w < 16; ++w) s |= dtr[w] & kv[w];
    bool nk = valid && (s == 0ull);
    u64 bal = __ballot(nk ? 1 : 0);
    __syncthreads();                       // A: all keepv/flag reads done
    if (lane == 0 && bal != kv[wv]) {
      keepv[wv] = bal;
      atomicOr(&changed2[pass & 1], 1u);
    }
    __syncthreads();                       // B: writes visible
    u32 ch = changed2[pass & 1];
    if (tid == 0) changed2[(pass & 1) ^ 1] = 0;  // reset OTHER slot (consumed
                                                 // last pass; reuse in 2)
    if (!ch) break;                        // ch uniform -> uniform exit
  }
  if (tid < MAXC) {
    bool kept = ((keepv[wv] >> lane) & 1ull) != 0ull;
    size_t o = (size_t)b * MAXC + tid;
    float4 bx = ((const float4*)selbox)[o];
    float* orow = out + o * 6;
    orow[0] = kept ? bx.x : 0.0f;
    orow[1] = kept ? bx.y : 0.0f;
    orow[2] = kept ? bx.z : 0.0f;
    orow[3] = kept ? bx.w : 0.0f;
    orow[4] = kept ? meta.x : 0.0f;
    orow[5] = kept ? meta.y : 0.0f;
    out[(size_t)BATCH * MAXC * 6 + o] = kept ? 1.0f : 0.0f;
  }
}

extern "C" void kernel_launch(void* const* d_in, const int* in_sizes, int n_in,
                              void* d_out, int out_size, void* d_ws, size_t ws_size,
                              hipStream_t stream) {
  const float* pred = (const float*)d_in[0];
  float* out = (float*)d_out;
  char* ws = (char*)d_ws;
  size_t off = 0;
  auto alloc = [&](size_t bytes) -> void* {
    void* p = ws + off;
    off = (off + bytes + 255) & ~(size_t)255;
    return p;
  };
  u32* keys32   = (u32*)alloc((size_t)BATCH * NANCH * 4);
  float* selbox = (float*)alloc((size_t)BATCH * MAXC * 4 * 4);
  float* offbox = (float*)alloc((size_t)BATCH * MAXC * 4 * 4);
  float2* selmeta = (float2*)alloc((size_t)BATCH * MAXC * 8);
  u64* dt       = (u64*)alloc((size_t)BATCH * 16 * MAXC * 8);
  (void)ws_size; (void)in_sizes; (void)n_in; (void)out_size;

  dim3 g1(NTILES, BATCH);
  k1_score<<<g1, 256, 0, stream>>>(pred, keys32);
  k2_select<<<BATCH, 1024, 0, stream>>>(pred, keys32, selbox, offbox, selmeta);
  k3_dt<<<(BATCH * MAXC) / 4, 256, 0, stream>>>((const float4*)offbox, dt);
  k4_jacobi<<<BATCH, 1024, 0, stream>>>(dt, selmeta, selbox, out);
}